// Round 5
// baseline (5038.695 us; speedup 1.0000x reference)
//
#include <hip/hip_runtime.h>
#include <math.h>

#define H0 384
#define W0 640
#define H1 192
#define W1 320
#define H2 96
#define W2 160
#define NP1 (H1*W1)   /* 61440 */
#define NP2 (H2*W2)   /* 15360 */
#define ND  48        /* MAX_DISP/4 */
#define NBLK2 (NP2/256)  /* 60 */
#define CHW ((size_t)32*NP2)
/* padded (halo=1) layout, global coords */
#define PW 162
#define PH 98
#define PSL (PH*PW)            /* 15876 */
#define PCHW ((size_t)32*PSL)  /* 508032 */

// ---------------- generic prep ----------------

__global__ void zero_buf_kernel(float* __restrict__ p, size_t n) {
    size_t i = (size_t)blockIdx.x*256 + threadIdx.x;
    size_t stride = (size_t)gridDim.x*256;
    for (; i < n; i += stride) p[i] = 0.f;
}

// out[(ci*K + k)*CO + co] = in[(co*CI + ci)*K + k]
__global__ void transpose_w_kernel(const float* __restrict__ in, float* __restrict__ out,
                                   int CI, int K, int CO) {
    int idx = blockIdx.x*256 + threadIdx.x;
    int total = CI*K*CO;
    if (idx >= total) return;
    int co = idx % CO;
    int t  = idx / CO;
    int k  = t % K;
    int ci = t / K;
    out[idx] = in[(co*CI + ci)*K + k];
}

// packed z/r weights, 4-co groups: entry e = (cg*64+ci)*9+k -> float4 pair {z co0..3},{r co0..3}
// combined for hx=[h,h,feat]: ci<32 -> w[:,ci]+w[:,ci+32]; ci in 32..63 -> w[:,ci+32]
__global__ void prep_zr_pk4(const float* __restrict__ wz, const float* __restrict__ wr,
                            float4* __restrict__ wpk) {
    int idx = blockIdx.x*256 + threadIdx.x;   // 8*64*9 = 4608
    if (idx >= 8*64*9) return;
    int k  = idx % 9;
    int ci = (idx/9) % 64;
    int cg = idx / (9*64);
    float z[4], r[4];
    #pragma unroll
    for (int j = 0; j < 4; ++j) {
        int co = cg*4 + j;
        if (ci < 32) {
            z[j] = wz[(co*96 + ci)*9 + k] + wz[(co*96 + ci + 32)*9 + k];
            r[j] = wr[(co*96 + ci)*9 + k] + wr[(co*96 + ci + 32)*9 + k];
        } else {
            z[j] = wz[(co*96 + ci + 32)*9 + k];
            r[j] = wr[(co*96 + ci + 32)*9 + k];
        }
    }
    wpk[2*idx]   = make_float4(z[0], z[1], z[2], z[3]);
    wpk[2*idx+1] = make_float4(r[0], r[1], r[2], r[3]);
}

// packed q weights, 4-co groups: entry e = (cg*96+ci)*9+k -> float4 {co0..3}
__global__ void prep_q_pk4(const float* __restrict__ wq, float4* __restrict__ qpk) {
    int idx = blockIdx.x*256 + threadIdx.x;   // 8*96*9 = 6912
    if (idx >= 8*96*9) return;
    int k  = idx % 9;
    int ci = (idx/9) % 96;
    int cg = idx / (9*96);
    float v[4];
    #pragma unroll
    for (int j = 0; j < 4; ++j) v[j] = wq[((cg*4+j)*96 + ci)*9 + k];
    qpk[idx] = make_float4(v[0], v[1], v[2], v[3]);
}

// hwork[c][py][px] = hidden[c][py-1][px-1] interior, 0 halo
__global__ void pad_init_kernel(const float* __restrict__ hidden, float* __restrict__ hwork) {
    int idx = blockIdx.x*256 + threadIdx.x;
    if (idx >= 32*PSL) return;
    int c = idx / PSL;
    int r = idx % PSL;
    int py = r / PW, px = r % PW;
    int y = py - 1, x = px - 1;
    float v = 0.f;
    if ((unsigned)y < (unsigned)H2 && (unsigned)x < (unsigned)W2)
        v = hidden[c*NP2 + y*W2 + x];
    hwork[idx] = v;
}

// ---------------- encoder kernels ----------------

__global__ void conv7s2_v2(const float* __restrict__ img, const float* __restrict__ wt,
                           const float* __restrict__ b, float* __restrict__ out) {
    int sp = blockIdx.x*256 + threadIdx.x;
    int oy = sp / W1, ox = sp % W1;
    float acc[32];
    #pragma unroll
    for (int j = 0; j < 32; ++j) acc[j] = b[j];
    for (int ci = 0; ci < 3; ++ci) {
        for (int ky = 0; ky < 7; ++ky) {
            int iy = 2*oy - 3 + ky;
            if ((unsigned)iy >= (unsigned)H0) continue;
            const float* row  = img + ci*(H0*W0) + iy*W0;
            const float* wrow = wt + (ci*49 + ky*7)*32;
            #pragma unroll
            for (int kx = 0; kx < 7; ++kx) {
                int ix = 2*ox - 3 + kx;
                if ((unsigned)ix >= (unsigned)W0) continue;
                float v = row[ix]*(2.0f/255.0f) - 1.0f;
                const float4* wp = (const float4*)(wrow + kx*32);
                #pragma unroll
                for (int j4 = 0; j4 < 8; ++j4) {
                    float4 w4 = wp[j4];
                    acc[4*j4+0] += v*w4.x; acc[4*j4+1] += v*w4.y;
                    acc[4*j4+2] += v*w4.z; acc[4*j4+3] += v*w4.w;
                }
            }
        }
    }
    #pragma unroll
    for (int j = 0; j < 32; ++j) out[j*NP1 + sp] = acc[j];
}

__global__ void stats_partial_kernel(const float* __restrict__ x, int N, float* __restrict__ st) {
    int c = blockIdx.x >> 3, sl = blockIdx.x & 7;
    int chunk = N >> 3;
    const float4* p = (const float4*)(x + (size_t)c*N + (size_t)sl*chunk);
    int n4 = chunk >> 2;
    float s = 0.f, s2 = 0.f;
    for (int i = threadIdx.x; i < n4; i += 256) {
        float4 v = p[i];
        s  += v.x + v.y + v.z + v.w;
        s2 += v.x*v.x + v.y*v.y + v.z*v.z + v.w*v.w;
    }
    __shared__ float sh1[256], sh2[256];
    sh1[threadIdx.x] = s; sh2[threadIdx.x] = s2;
    __syncthreads();
    for (int o = 128; o > 0; o >>= 1) {
        if (threadIdx.x < o) { sh1[threadIdx.x] += sh1[threadIdx.x+o]; sh2[threadIdx.x] += sh2[threadIdx.x+o]; }
        __syncthreads();
    }
    if (threadIdx.x == 0) { atomicAdd(&st[2*c], sh1[0]); atomicAdd(&st[2*c+1], sh2[0]); }
}

__global__ void norm_relu_v2(float* __restrict__ x, const float* __restrict__ st, int N) {
    int c = blockIdx.y;
    float m    = st[2*c] / (float)N;
    float var  = st[2*c+1] / (float)N - m*m;
    float rstd = rsqrtf(var + 1e-5f);
    float4* p = (float4*)(x + (size_t)c*N);
    int i = blockIdx.x*256 + threadIdx.x;
    float4 v = p[i];
    v.x = fmaxf((v.x-m)*rstd, 0.f); v.y = fmaxf((v.y-m)*rstd, 0.f);
    v.z = fmaxf((v.z-m)*rstd, 0.f); v.w = fmaxf((v.w-m)*rstd, 0.f);
    p[i] = v;
}

__global__ void conv3s2_v2(const float* __restrict__ in, const float* __restrict__ wt,
                           const float* __restrict__ b, float* __restrict__ out) {
    int cg = blockIdx.x / (NP2/256);
    int sp = (blockIdx.x % (NP2/256))*256 + threadIdx.x;
    int co8 = cg*8;
    int oy = sp / W2, ox = sp % W2;
    float acc[8];
    #pragma unroll
    for (int j = 0; j < 8; ++j) acc[j] = b[co8+j];
    for (int ci = 0; ci < 32; ++ci) {
        const float* ip  = in + ci*NP1;
        const float* wci = wt + ci*9*32 + co8;
        #pragma unroll
        for (int ky = 0; ky < 3; ++ky) {
            int iy = 2*oy - 1 + ky;
            if ((unsigned)iy >= (unsigned)H1) continue;
            const float* row = ip + iy*W1;
            #pragma unroll
            for (int kx = 0; kx < 3; ++kx) {
                int ix = 2*ox - 1 + kx;
                if ((unsigned)ix >= (unsigned)W1) continue;
                float v = row[ix];
                const float4* wp = (const float4*)(wci + (ky*3+kx)*32);
                float4 w0 = wp[0], w1 = wp[1];
                acc[0] += v*w0.x; acc[1] += v*w0.y; acc[2] += v*w0.z; acc[3] += v*w0.w;
                acc[4] += v*w1.x; acc[5] += v*w1.y; acc[6] += v*w1.z; acc[7] += v*w1.w;
            }
        }
    }
    #pragma unroll
    for (int j = 0; j < 8; ++j) out[(co8+j)*NP2 + sp] = acc[j];
}

__global__ void conv1x1_v2(const float* __restrict__ in, const float* __restrict__ wt,
                           const float* __restrict__ b, float* __restrict__ out, int mode) {
    int cg = blockIdx.x / (NP2/256);
    int sp = (blockIdx.x % (NP2/256))*256 + threadIdx.x;
    int co8 = cg*8;
    float acc[8];
    #pragma unroll
    for (int j = 0; j < 8; ++j) acc[j] = b[co8+j];
    for (int ci = 0; ci < 32; ++ci) {
        float v = in[ci*NP2 + sp];
        const float4* wp = (const float4*)(wt + ci*32 + co8);
        float4 w0 = wp[0], w1 = wp[1];
        acc[0] += v*w0.x; acc[1] += v*w0.y; acc[2] += v*w0.z; acc[3] += v*w0.w;
        acc[4] += v*w1.x; acc[5] += v*w1.y; acc[6] += v*w1.z; acc[7] += v*w1.w;
    }
    #pragma unroll
    for (int j = 0; j < 8; ++j) {
        float a = acc[j];
        if (mode) a = tanhf(a);
        out[(co8+j)*NP2 + sp] = a;
    }
}

// ---------------- feat precompute (padded, global coords) ----------------

// nd slices starting at d0; grid = nd*4*NBLK2; thread: 1 px, 8 co
__global__ void featall_pad_kernel(const float* __restrict__ fmap1, const float* __restrict__ fmap2,
                                   const float* __restrict__ wat, const float* __restrict__ wbt,
                                   const float* __restrict__ wct, const float* __restrict__ bc,
                                   float* __restrict__ featpad, int d0) {
    int bid = blockIdx.x;
    int dsl = bid / (4*NBLK2);
    int rem = bid % (4*NBLK2);
    int cg  = rem / NBLK2;
    int sp  = (rem % NBLK2)*256 + threadIdx.x;
    int d = d0 + dsl;
    int y = sp / W2;
    int gx = sp % W2;
    if (gx < d) return;
    int co8 = cg*8;
    float acc[8];
    #pragma unroll
    for (int j = 0; j < 8; ++j) acc[j] = bc[co8+j];
    for (int ci = 0; ci < 32; ++ci) {
        float f1 = fmap1[ci*NP2 + sp];          // global gx
        float f2 = fmap2[ci*NP2 + sp - d];      // gx - d
        float f12 = f1*f2;
        const float4* ap = (const float4*)(wat + ci*32 + co8);
        const float4* bp = (const float4*)(wbt + ci*32 + co8);
        const float4* cp = (const float4*)(wct + ci*32 + co8);
        float4 a0 = ap[0], a1 = ap[1];
        float4 b0 = bp[0], b1 = bp[1];
        float4 c0 = cp[0], c1 = cp[1];
        acc[0] += f1*a0.x + f2*b0.x + f12*c0.x;
        acc[1] += f1*a0.y + f2*b0.y + f12*c0.y;
        acc[2] += f1*a0.z + f2*b0.z + f12*c0.z;
        acc[3] += f1*a0.w + f2*b0.w + f12*c0.w;
        acc[4] += f1*a1.x + f2*b1.x + f12*c1.x;
        acc[5] += f1*a1.y + f2*b1.y + f12*c1.y;
        acc[6] += f1*a1.z + f2*b1.z + f12*c1.z;
        acc[7] += f1*a1.w + f2*b1.w + f12*c1.w;
    }
    float* dst = featpad + (size_t)dsl*PCHW + (size_t)(y+1)*PW + (gx+1);
    #pragma unroll
    for (int j = 0; j < 8; ++j) dst[(size_t)(co8+j)*PSL] = acc[j];
}

// ---------------- GRU loop kernels ----------------

// z,r 3x3 convs over padded {hwork, featpad_d}; thread: 1 px x 4 co; 480 blocks
__global__ __launch_bounds__(256, 4)
void zr_v4(const float* __restrict__ hwork, const float* __restrict__ featd,
           const float* __restrict__ hidden,
           const float4* __restrict__ wpk, const float* __restrict__ bz,
           const float* __restrict__ br, float* __restrict__ zbuf,
           float* __restrict__ rhpad, int d) {
    __shared__ float4 lw[2*64*9];
    int cg = blockIdx.x / NBLK2;
    int sp = (blockIdx.x % NBLK2)*256 + threadIdx.x;
    for (int i = threadIdx.x; i < 1152; i += 256) lw[i] = wpk[cg*1152 + i];
    __syncthreads();
    int y = sp / W2;
    int gx = sp % W2;
    if (gx < d) return;
    int co0 = cg*4;
    float az[4], ar[4];
    #pragma unroll
    for (int j = 0; j < 4; ++j) { az[j] = bz[co0+j]; ar[j] = br[co0+j]; }
    int poff = (y+1)*PW + (gx+1);
    const float* bases[2] = { hwork + poff, featd + poff };
    #pragma unroll 1
    for (int pass = 0; pass < 2; ++pass) {
        const float* p = bases[pass];
        const float4* wp = lw + pass*32*18;
        #pragma unroll 1
        for (int ci = 0; ci < 32; ++ci) {
            float v[9];
            v[0] = p[-PW-1]; v[1] = p[-PW]; v[2] = p[-PW+1];
            v[3] = p[-1];    v[4] = p[0];   v[5] = p[1];
            v[6] = p[PW-1];  v[7] = p[PW];  v[8] = p[PW+1];
            #pragma unroll
            for (int k = 0; k < 9; ++k) {
                float4 wz4 = wp[2*k];
                float4 wr4 = wp[2*k+1];
                float vv = v[k];
                az[0] += vv*wz4.x; az[1] += vv*wz4.y; az[2] += vv*wz4.z; az[3] += vv*wz4.w;
                ar[0] += vv*wr4.x; ar[1] += vv*wr4.y; ar[2] += vv*wr4.z; ar[3] += vv*wr4.w;
            }
            p += PSL;
            wp += 18;
        }
    }
    #pragma unroll
    for (int j = 0; j < 4; ++j) {
        int co = co0 + j;
        float z = 1.f/(1.f + __expf(-az[j]));
        float r = 1.f/(1.f + __expf(-ar[j]));
        float h = hidden[(size_t)co*NP2 + sp];
        zbuf[(size_t)co*NP2 + sp] = z;
        rhpad[(size_t)co*PSL + poff] = r*h;
    }
}

// q = tanh(conv3x3 over padded {rhpad, hwork, featpad_d}); thread: 1 px x 4 co; 480 blocks
__global__ __launch_bounds__(256, 4)
void q_v4(const float* __restrict__ rhpad, const float* __restrict__ hwork,
          const float* __restrict__ featd, const float4* __restrict__ qpk,
          const float* __restrict__ bq, float* __restrict__ qbuf, int d) {
    __shared__ float4 lw[96*9];
    int cg = blockIdx.x / NBLK2;
    int sp = (blockIdx.x % NBLK2)*256 + threadIdx.x;
    for (int i = threadIdx.x; i < 864; i += 256) lw[i] = qpk[cg*864 + i];
    __syncthreads();
    int y = sp / W2;
    int gx = sp % W2;
    if (gx < d) return;
    int co0 = cg*4;
    float a[4];
    #pragma unroll
    for (int j = 0; j < 4; ++j) a[j] = bq[co0+j];
    int poff = (y+1)*PW + (gx+1);
    const float* bases[3] = { rhpad + poff, hwork + poff, featd + poff };
    #pragma unroll 1
    for (int pass = 0; pass < 3; ++pass) {
        const float* p = bases[pass];
        const float4* wp = lw + pass*32*9;
        #pragma unroll 1
        for (int ci = 0; ci < 32; ++ci) {
            float v[9];
            v[0] = p[-PW-1]; v[1] = p[-PW]; v[2] = p[-PW+1];
            v[3] = p[-1];    v[4] = p[0];   v[5] = p[1];
            v[6] = p[PW-1];  v[7] = p[PW];  v[8] = p[PW+1];
            #pragma unroll
            for (int k = 0; k < 9; ++k) {
                float4 w = wp[k];
                float vv = v[k];
                a[0] += vv*w.x; a[1] += vv*w.y; a[2] += vv*w.z; a[3] += vv*w.w;
            }
            p += PSL;
            wp += 9;
        }
    }
    #pragma unroll
    for (int j = 0; j < 4; ++j)
        qbuf[(size_t)(co0+j)*NP2 + sp] = tanhf(a[j]);
}

// hidden[:, :, d:] = (1-z)*h + z*q; maintain hwork/rhpad marching zero column at gx==d
__global__ void update_v4(float* __restrict__ hidden, float* __restrict__ hwork,
                          float* __restrict__ rhpad, const float* __restrict__ zbuf,
                          const float* __restrict__ qbuf, int d, int total) {
    int idx = blockIdx.x*256 + threadIdx.x;
    if (idx >= total) return;
    int Wd = W2 - d;
    int lx = idx % Wd;
    int rest = idx / Wd;          // co*H2 + y
    int co = rest / H2;
    int y  = rest % H2;
    int gx = lx + d;
    int off = rest*W2 + gx;
    float h = hidden[off];
    float z = zbuf[off];
    float q = qbuf[off];
    float hn = (1.0f - z)*h + z*q;
    hidden[off] = hn;
    int pidx = co*PSL + (y+1)*PW + (gx+1);
    if (lx == 0) {
        hwork[pidx] = 0.f;    // left halo for iteration d+1
        rhpad[pidx] = 0.f;
    } else {
        hwork[pidx] = hn;
    }
}

// ---------------- disparity head ----------------

__global__ void disp1_v2(const float* __restrict__ hidden, const float* __restrict__ wt,
                         const float* __restrict__ b, float* __restrict__ out) {
    int cg = blockIdx.x / (NP2/256);
    int sp = (blockIdx.x % (NP2/256))*256 + threadIdx.x;
    int co8 = cg*8;
    int y = sp / W2, x = sp % W2;
    float acc[8];
    #pragma unroll
    for (int j = 0; j < 8; ++j) acc[j] = b[co8+j];
    for (int ci = 0; ci < 32; ++ci) {
        const float* ip = hidden + ci*NP2;
        #pragma unroll
        for (int dy = 0; dy < 3; ++dy) {
            int ys = y + dy - 1;
            if ((unsigned)ys >= (unsigned)H2) continue;
            const float* row = ip + ys*W2;
            #pragma unroll
            for (int dx = 0; dx < 3; ++dx) {
                int xs = x + dx - 1;
                if ((unsigned)xs >= (unsigned)W2) continue;
                float v = row[xs];
                const float4* wp = (const float4*)(wt + (ci*9 + dy*3 + dx)*64 + co8);
                float4 w0 = wp[0], w1 = wp[1];
                acc[0] += v*w0.x; acc[1] += v*w0.y; acc[2] += v*w0.z; acc[3] += v*w0.w;
                acc[4] += v*w1.x; acc[5] += v*w1.y; acc[6] += v*w1.z; acc[7] += v*w1.w;
            }
        }
    }
    #pragma unroll
    for (int j = 0; j < 8; ++j) out[(co8+j)*NP2 + sp] = fmaxf(acc[j], 0.f);
}

// disp2 stage A: 8 ci-groups x 60 blocks; partial sums (no bias)
__global__ void disp2_part_kernel(const float* __restrict__ in, const float* __restrict__ w,
                                  float* __restrict__ part) {
    __shared__ float lw[8*9];
    int g  = blockIdx.x / NBLK2;
    int sp = (blockIdx.x % NBLK2)*256 + threadIdx.x;
    if (threadIdx.x < 72) lw[threadIdx.x] = w[g*72 + threadIdx.x];
    __syncthreads();
    int y = sp / W2, x = sp % W2;
    float acc = 0.f;
    #pragma unroll
    for (int ci = 0; ci < 8; ++ci) {
        const float* ip = in + (g*8 + ci)*NP2;
        #pragma unroll
        for (int dy = 0; dy < 3; ++dy) {
            int ys = y+dy-1; if ((unsigned)ys >= (unsigned)H2) continue;
            const float* row = ip + ys*W2;
            #pragma unroll
            for (int dx = 0; dx < 3; ++dx) {
                int xs = x+dx-1; if ((unsigned)xs >= (unsigned)W2) continue;
                acc += lw[ci*9+dy*3+dx] * row[xs];
            }
        }
    }
    part[g*NP2 + sp] = acc;
}

// disp2 stage B: combine + bias + negate
__global__ void disp2_comb_kernel(const float* __restrict__ part, const float* __restrict__ b,
                                  float* __restrict__ out) {
    int sp = blockIdx.x*256 + threadIdx.x;
    float acc = b[0];
    #pragma unroll
    for (int g = 0; g < 8; ++g) acc += part[g*NP2 + sp];
    out[sp] = -acc;
}

// ---------------- launch ----------------

extern "C" void kernel_launch(void* const* d_in, const int* in_sizes, int n_in,
                              void* d_out, int out_size, void* d_ws, size_t ws_size,
                              hipStream_t stream) {
    const float* image1   = (const float*)d_in[0];
    const float* image2   = (const float*)d_in[1];
    const float* fnet_w1  = (const float*)d_in[2];
    const float* fnet_b1  = (const float*)d_in[3];
    const float* fnet_w2  = (const float*)d_in[4];
    const float* fnet_b2  = (const float*)d_in[5];
    const float* fnet_w3  = (const float*)d_in[6];
    const float* fnet_b3  = (const float*)d_in[7];
    const float* cnet_w1  = (const float*)d_in[8];
    const float* cnet_b1  = (const float*)d_in[9];
    const float* cnet_w2  = (const float*)d_in[10];
    const float* cnet_b2  = (const float*)d_in[11];
    const float* cnet_w3  = (const float*)d_in[12];
    const float* cnet_b3  = (const float*)d_in[13];
    const float* bform_a  = (const float*)d_in[14];
    const float* bform_b  = (const float*)d_in[15];
    const float* bform_cd_w = (const float*)d_in[16];
    const float* bform_cd_b = (const float*)d_in[17];
    const float* gru_wz   = (const float*)d_in[18];
    const float* gru_bz   = (const float*)d_in[19];
    const float* gru_wr   = (const float*)d_in[20];
    const float* gru_br   = (const float*)d_in[21];
    const float* gru_wq   = (const float*)d_in[22];
    const float* gru_bq   = (const float*)d_in[23];
    const float* disp_w1  = (const float*)d_in[24];
    const float* disp_b1  = (const float*)d_in[25];
    const float* disp_w2  = (const float*)d_in[26];
    const float* disp_b2  = (const float*)d_in[27];

    float* ws = (float*)d_ws;
    size_t o = 0;
    float* e1     = ws + o; o += (size_t)32*NP1;
    float* e2     = ws + o; o += CHW;
    float* fmap1  = ws + o; o += CHW;
    float* fmap2  = ws + o; o += CHW;
    float* hidden = ws + o; o += CHW;
    float* zbuf   = ws + o; o += CHW;
    float* qbuf   = ws + o; o += CHW;
    float* hwork  = ws + o; o += PCHW;
    float* rhpad  = ws + o; o += PCHW;
    float* stats  = ws + o; o += 384;
    float* wzr4   = ws + o; o += 8*64*9*8;
    float* wq4    = ws + o; o += 8*96*9*4;
    float* we1f   = ws + o; o += 3*49*32;
    float* we1c   = ws + o; o += 3*49*32;
    float* we2f   = ws + o; o += 32*9*32;
    float* we2c   = ws + o; o += 32*9*32;
    float* w3f    = ws + o; o += 32*32;
    float* w3c    = ws + o; o += 32*32;
    float* wat    = ws + o; o += 32*32;
    float* wbt    = ws + o; o += 32*32;
    float* wct    = ws + o; o += 32*32;
    float* wd1t   = ws + o; o += 32*9*64;
    float* featpad = ws + o;                 // ND*PCHW if it fits, else 1*PCHW
    bool fullFeat = ws_size >= (o + (size_t)ND*PCHW) * sizeof(float);
    float* disp1buf = e1;     // e1 dead after encoders (64*NP2 <= 32*NP1)
    float* disp2part = e2;    // e2 dead after encoders (8*NP2 <= 32*NP2)

    // --- prep ---
    zero_buf_kernel<<<2, 256, 0, stream>>>(stats, 384);
    transpose_w_kernel<<<(3*49*32+255)/256, 256, 0, stream>>>(fnet_w1, we1f, 3, 49, 32);
    transpose_w_kernel<<<(3*49*32+255)/256, 256, 0, stream>>>(cnet_w1, we1c, 3, 49, 32);
    transpose_w_kernel<<<(32*9*32+255)/256, 256, 0, stream>>>(fnet_w2, we2f, 32, 9, 32);
    transpose_w_kernel<<<(32*9*32+255)/256, 256, 0, stream>>>(cnet_w2, we2c, 32, 9, 32);
    transpose_w_kernel<<<4, 256, 0, stream>>>(fnet_w3, w3f, 32, 1, 32);
    transpose_w_kernel<<<4, 256, 0, stream>>>(cnet_w3, w3c, 32, 1, 32);
    transpose_w_kernel<<<4, 256, 0, stream>>>(bform_a, wat, 32, 1, 32);
    transpose_w_kernel<<<4, 256, 0, stream>>>(bform_b, wbt, 32, 1, 32);
    transpose_w_kernel<<<4, 256, 0, stream>>>(bform_cd_w, wct, 32, 1, 32);
    transpose_w_kernel<<<(32*9*64+255)/256, 256, 0, stream>>>(disp_w1, wd1t, 32, 9, 64);
    prep_zr_pk4<<<(8*64*9+255)/256, 256, 0, stream>>>(gru_wz, gru_wr, (float4*)wzr4);
    prep_q_pk4<<<(8*96*9+255)/256, 256, 0, stream>>>(gru_wq, (float4*)wq4);

    // --- encoders (B=1: inorm == bnorm) ---
    auto encoder = [&](const float* img, const float* w1t, const float* b1,
                       const float* w2t, const float* b2,
                       const float* w3t, const float* b3, float* dst, int mode,
                       float* st1, float* st2) {
        conv7s2_v2<<<NP1/256, 256, 0, stream>>>(img, w1t, b1, e1);
        stats_partial_kernel<<<256, 256, 0, stream>>>(e1, NP1, st1);
        norm_relu_v2<<<dim3(NP1/1024, 32), 256, 0, stream>>>(e1, st1, NP1);
        conv3s2_v2<<<4*(NP2/256), 256, 0, stream>>>(e1, w2t, b2, e2);
        stats_partial_kernel<<<256, 256, 0, stream>>>(e2, NP2, st2);
        norm_relu_v2<<<dim3(NP2/1024, 32), 256, 0, stream>>>(e2, st2, NP2);
        conv1x1_v2<<<4*(NP2/256), 256, 0, stream>>>(e2, w3t, b3, dst, mode);
    };
    encoder(image1, we1f, fnet_b1, we2f, fnet_b2, w3f, fnet_b3, fmap1, 0, stats+0,   stats+64);
    encoder(image2, we1f, fnet_b1, we2f, fnet_b2, w3f, fnet_b3, fmap2, 0, stats+128, stats+192);
    encoder(image1, we1c, cnet_b1, we2c, cnet_b2, w3c, cnet_b3, hidden, 1, stats+256, stats+320);

    // --- padded working buffers ---
    pad_init_kernel<<<(32*PSL+255)/256, 256, 0, stream>>>(hidden, hwork);
    zero_buf_kernel<<<1024, 256, 0, stream>>>(rhpad, PCHW);

    // --- feat precompute ---
    if (fullFeat) {
        zero_buf_kernel<<<2048, 256, 0, stream>>>(featpad, (size_t)ND*PCHW);
        featall_pad_kernel<<<ND*4*NBLK2, 256, 0, stream>>>(fmap1, fmap2, wat, wbt, wct,
                                                           bform_cd_b, featpad, 0);
    }

    // --- sequential GRU sweep over disparities ---
    for (int d = 0; d < ND; ++d) {
        const float* featd;
        if (fullFeat) {
            featd = featpad + (size_t)d*PCHW;
        } else {
            zero_buf_kernel<<<1024, 256, 0, stream>>>(featpad, PCHW);
            featall_pad_kernel<<<4*NBLK2, 256, 0, stream>>>(fmap1, fmap2, wat, wbt, wct,
                                                            bform_cd_b, featpad, d);
            featd = featpad;
        }
        zr_v4<<<8*NBLK2, 256, 0, stream>>>(hwork, featd, hidden, (const float4*)wzr4,
                                           gru_bz, gru_br, zbuf, rhpad, d);
        q_v4<<<8*NBLK2, 256, 0, stream>>>(rhpad, hwork, featd, (const float4*)wq4,
                                          gru_bq, qbuf, d);
        int tot = 32*H2*(W2 - d);
        update_v4<<<(tot + 255)/256, 256, 0, stream>>>(hidden, hwork, rhpad,
                                                       zbuf, qbuf, d, tot);
    }

    // --- disparity head ---
    disp1_v2<<<8*(NP2/256), 256, 0, stream>>>(hidden, wd1t, disp_b1, disp1buf);
    disp2_part_kernel<<<8*NBLK2, 256, 0, stream>>>(disp1buf, disp_w2, disp2part);
    disp2_comb_kernel<<<NBLK2, 256, 0, stream>>>(disp2part, disp_b2, (float*)d_out);
}